// Round 1
// baseline (184.614 us; speedup 1.0000x reference)
//
#include <hip/hip_runtime.h>
#include <hip/hip_bf16.h>
#include <cstdint>

typedef __attribute__((ext_vector_type(8))) short bf16x8;
typedef __attribute__((ext_vector_type(4))) float f32x4;

constexpr int Bb = 16, Hh = 8, Tt = 12, Nn = 325, DKk = 32;
constexpr int NSLICE = Bb * Hh * Tt;      // 1536
constexpr int SLICE  = Nn * DKk;          // 10400
constexpr int BIASE  = Nn * Nn;           // 105625
constexpr int KSTR = 40;                  // K LDS row stride (elems): 20-dword bank stride -> 2-way (free)
constexpr int VSTR = 360;                 // V^T LDS row stride (elems)
constexpr int PSTR = 40;                  // P tile row stride
constexpr int NT = 21;                    // ceil(325/16)

__device__ __forceinline__ unsigned short f2bf(float f) {
  union { float f; uint32_t u; } v; v.f = f;
  uint32_t u = v.u;
  uint32_t r = u + 0x7FFFu + ((u >> 16) & 1u);   // RNE
  return (unsigned short)(r >> 16);
}
__device__ __forceinline__ uint32_t pack2(float a, float b) {
  return (uint32_t)f2bf(a) | ((uint32_t)f2bf(b) << 16);
}

__global__ __launch_bounds__(256, 2)
void attn_kernel(const float* __restrict__ Q, const float* __restrict__ K,
                 const float* __restrict__ V, const float* __restrict__ Bias,
                 float* __restrict__ Out)
{
  __shared__ short lds_k[336 * KSTR];      // 26.9 KB  (rows 325..335 uninit -> masked)
  __shared__ short lds_vt[32 * VSTR];      // 23.0 KB  (V transposed, bf16)
  __shared__ short lds_p[4][16 * PSTR];    // 5.1 KB   (per-wave P tile)

  const int s = blockIdx.x;
  const int bh = s / Tt;                   // bias broadcast over T
  const size_t base  = (size_t)s * SLICE;
  const size_t bbase = (size_t)bh * BIASE;
  const int tid = threadIdx.x;

  // ---- stage K as bf16, row-major padded ----
  for (int i = tid; i < SLICE / 2; i += 256) {
    const int e0 = i << 1;
    const int row = e0 >> 5, col = e0 & 31;
    const float2 f = *(const float2*)(K + base + e0);
    *(uint32_t*)&lds_k[row * KSTR + col] = pack2(f.x, f.y);
  }
  // ---- stage V^T as bf16 (pack 2 consecutive j) ----
  for (int i = tid; i < 32 * 163; i += 256) {
    const int d = i & 31, jp = i >> 5;
    const int j0 = jp << 1;
    const float a  = V[base + (size_t)j0 * DKk + d];
    const float b2 = (j0 + 1 < Nn) ? V[base + (size_t)(j0 + 1) * DKk + d] : 0.f;
    *(uint32_t*)&lds_vt[d * VSTR + j0] = pack2(a, b2);
  }
  // ---- zero V^T pad cols 326..359 (kb=10 reads up to col 351; avoid 0*NaN) ----
  for (int i = tid; i < 32 * 34; i += 256) {
    const int d = i / 34, c = 326 + (i - d * 34);
    lds_vt[d * VSTR + c] = 0;
  }
  __syncthreads();

  const int wave = tid >> 6, lane = tid & 63;
  const int r16 = lane & 15, grp = lane >> 4;
  const float scale = 0.17677669529663687f;      // 1/sqrt(32), folded into Q
  short* __restrict__ pbuf = lds_p[wave];

  for (int qt = wave; qt < NT; qt += 4) {
    const int qb = qt << 4;
    const int qrow = qb + r16;
    const int qrc = qrow < Nn ? qrow : (Nn - 1);
    // Q fragment straight from global (A-layout: row=lane&15, k=(lane>>4)*8+e)
    const float* qp = Q + base + (size_t)qrc * DKk + grp * 8;
    const float4 q0 = *(const float4*)qp;
    const float4 q1 = *(const float4*)(qp + 4);
    bf16x8 aq;
    aq[0] = (short)f2bf(q0.x * scale); aq[1] = (short)f2bf(q0.y * scale);
    aq[2] = (short)f2bf(q0.z * scale); aq[3] = (short)f2bf(q0.w * scale);
    aq[4] = (short)f2bf(q1.x * scale); aq[5] = (short)f2bf(q1.y * scale);
    aq[6] = (short)f2bf(q1.z * scale); aq[7] = (short)f2bf(q1.w * scale);

    f32x4 acc0 = (f32x4)(0.f), acc1 = (f32x4)(0.f);
    float rs[4] = {0.f, 0.f, 0.f, 0.f};
    const int prow0 = qb + grp * 4;                // first C/D row this lane owns

    for (int kb = 0; kb < 11; ++kb) {
      #pragma unroll
      for (int h = 0; h < 2; ++h) {
        const int jt = (kb << 1) + h;
        if (jt < NT) {
          const int jb = jt << 4;
          const bf16x8 bk = *(const bf16x8*)&lds_k[(jb + r16) * KSTR + grp * 8];
          f32x4 sv = __builtin_amdgcn_mfma_f32_16x16x32_bf16(aq, bk, (f32x4)(0.f), 0, 0, 0);
          const int col  = jb + r16;               // C/D: col = lane&15
          const int colc = col < Nn ? col : (Nn - 1);
          const bool cok = col < Nn;
          #pragma unroll
          for (int m = 0; m < 4; ++m) {            // C/D: row = (lane>>4)*4 + m
            const int row  = prow0 + m;
            const int rowc = row < Nn ? row : (Nn - 1);
            float x = sv[m] + Bias[bbase + (size_t)rowc * Nn + colc];
            x = cok ? x : -1e30f;                  // mask pad cols -> p = 0
            const float p = __expf(x);             // no max-subtract: scores ~N(0,1.4), safe in fp32
            rs[m] += p;
            pbuf[(grp * 4 + m) * PSTR + (h << 4) + r16] = (short)f2bf(p);
          }
        } else {                                   // jt == 21: zero P cols 16..31 of kb=10
          #pragma unroll
          for (int m = 0; m < 4; ++m)
            pbuf[(grp * 4 + m) * PSTR + (h << 4) + r16] = 0;
        }
      }
      // PV k-step (k = 32 keys): A = P tile (LDS transpose), B = V^T rows
      const bf16x8 ap  = *(const bf16x8*)&pbuf[r16 * PSTR + grp * 8];
      const bf16x8 bv0 = *(const bf16x8*)&lds_vt[r16 * VSTR + (kb << 5) + grp * 8];
      const bf16x8 bv1 = *(const bf16x8*)&lds_vt[(16 + r16) * VSTR + (kb << 5) + grp * 8];
      acc0 = __builtin_amdgcn_mfma_f32_16x16x32_bf16(ap, bv0, acc0, 0, 0, 0);
      acc1 = __builtin_amdgcn_mfma_f32_16x16x32_bf16(ap, bv1, acc1, 0, 0, 0);
    }

    // row sums: reduce across the 16-lane group (cols), then normalize + store
    #pragma unroll
    for (int m = 0; m < 4; ++m) {
      #pragma unroll
      for (int off = 1; off < 16; off <<= 1)
        rs[m] += __shfl_xor(rs[m], off);
    }
    #pragma unroll
    for (int m = 0; m < 4; ++m) {
      const int row = prow0 + m;
      if (row < Nn) {
        const float inv = 1.f / rs[m];
        Out[base + (size_t)row * DKk + r16]      = acc0[m] * inv;
        Out[base + (size_t)row * DKk + 16 + r16] = acc1[m] * inv;
      }
    }
  }
}

extern "C" void kernel_launch(void* const* d_in, const int* in_sizes, int n_in,
                              void* d_out, int out_size, void* d_ws, size_t ws_size,
                              hipStream_t stream) {
  const float* Q    = (const float*)d_in[0];
  const float* K    = (const float*)d_in[1];
  const float* V    = (const float*)d_in[2];
  const float* Bias = (const float*)d_in[3];
  float* Out = (float*)d_out;
  attn_kernel<<<dim3(NSLICE), dim3(256), 0, stream>>>(Q, K, V, Bias, Out);
}